// Round 7
// baseline (443.343 us; speedup 1.0000x reference)
//
#include <hip/hip_runtime.h>
#include <hip/hip_bf16.h>
#include <math.h>

constexpr int D  = 64;
constexpr int T  = 200;
constexpr int H0 = 80;
constexpr int H1 = 40;
constexpr int BLOCK = 256;
constexpr float NEG_INF_V = -4294967295.0f;

typedef short short8 __attribute__((ext_vector_type(8)));
typedef float f32x4 __attribute__((ext_vector_type(4)));
typedef int   int4v __attribute__((ext_vector_type(4)));

// RNE fp32->bf16 (hardware cvt), raw bits
__device__ inline unsigned short bf16h(float x) {
    __hip_bfloat16 t = __float2bfloat16(x);
    union { __hip_bfloat16 v; unsigned short u; } c; c.v = t; return c.u;
}
// RNE packed pair: low16 = bf16(a), high16 = bf16(b)
__device__ inline unsigned pk_bf16(float a, float b) {
    float2 f2; f2.x = a; f2.y = b;
    __hip_bfloat162 t = __float22bfloat162_rn(f2);
    union { __hip_bfloat162 v; unsigned u; } c; c.v = t; return c.u;
}
// split pair to (hi word, lo word)
__device__ inline void pk_split(float a, float b, unsigned& hi, unsigned& lo) {
    hi = pk_bf16(a, b);
    const float e0 = a - __uint_as_float(hi << 16);
    const float e1 = b - __uint_as_float(hi & 0xffff0000u);
    lo = pk_bf16(e0, e1);
}
__device__ inline short8 mk8(int w0, int w1, int w2, int w3) {
    union { int4v i; short8 s; } u;
    u.i = (int4v){w0, w1, w2, w3};
    return u.s;
}
#define BPERM(ad, v) __builtin_amdgcn_ds_bpermute((ad), (int)(v))
#define MFMA(A, B, C) __builtin_amdgcn_mfma_f32_16x16x32_bf16((A), (B), (C), 0, 0, 0)

// ============ Pre-kernel: fold W1 into split-bf16 B-frags in ws ============
// Batch-independent (18.4 KB -> L2-resident for the main kernel).
// B-frag layout (16x16x32): frag (k2s,nt2), lane holds B[k2=k2s*32+quad*8+j]
// [n=nt2*16+l16]; zero-padded 96x48 (pad rows/cols EXACTLY 0.0 -> main kernel
// may feed garbage-but-finite A there).
__global__ __launch_bounds__(256) void fold_w1(
    const float* __restrict__ W1, short* __restrict__ w1fHi,
    short* __restrict__ w1fLo)
{
    const int tid = threadIdx.x;
    for (int e = tid; e < 4608; e += 256) {
        const int k2 = e / 48, n = e - k2 * 48;
        const float w = (k2 < H0 && n < H1) ? W1[k2 * H1 + n] : 0.0f;
        const unsigned short hb = bf16h(w);
        const unsigned short lb = bf16h(w - __uint_as_float((unsigned)hb << 16));
        const int off = (((k2 >> 5) * 3 + (n >> 4)) << 9)
                      + (((((k2 >> 3) & 3) << 4) + (n & 15)) << 3) + (k2 & 7);
        w1fHi[off] = hb; w1fLo[off] = lb;
    }
}

// ============ Fully fused main kernel ============
// One block per batch b, 4 waves, LDS ~24.6 KB, target VGPR<=128 w/ NO scratch.
// Phase 0: fold weff[kk][h] = W0[64+kk][h]-W0[128+kk][h]+q_kk*W0[192+kk][h]
//   into split-bf16 MFMA A-frags in LDS (m=h, k=kk); biasq[h] = b0[h] +
//   sum_d q_d*(W0[d][h]+W0[128+d][h]). Mask + first k-tile issued BEFORE the
//   fold. W1 B-frags come from ws via coalesced loop-invariant 16B global
//   loads (L2-resident; no LDS).
// Phase 1: wave w owns M-tiles {w, w+4, ...} of 13 (M=200 pad 208).
//   Layer1: C1^T = weff(A) x K^T(B): lane holds h0[h=ht*16+quad*4+reg][m=l16];
//   PReLU in-register; pack to split-bf16 named uint2 scalars. kc0..3
//   reloaded IN PLACE for tile mt+4 right after KBUILD consumes them.
//   Layer2 INTERLEAVED per k2-slice: TRN (quad-level ds_bpermute transpose)
//   produces ONE a2hi/a2lo pair, immediately consumed by 9 MFMAs into 3
//   persistent f32x4 accumulators; the source hw/lw pair dies -> ~30 fewer
//   live VGPRs than all-TRN-then-all-L2 (R6's layout spilled ~21MB).
//   k2s=2 feeds TRN(hw4,hw4): garbage upper half multiplies the ZERO pad
//   rows of the W1 frags (finite x 0 = 0). Head dot + shfl_xor -> s_logits.
// Phase 2: softmax over T + out[b,d] = sum_t w_t v[b,t,d].
__global__ __launch_bounds__(BLOCK, 4) void attn_fused(
    const float* __restrict__ q, const float* __restrict__ k,
    const float* __restrict__ v, const float* __restrict__ W0,
    const float* __restrict__ b0, const float* __restrict__ a0,
    const short* __restrict__ w1fHi, const short* __restrict__ w1fLo,
    const float* __restrict__ b1, const float* __restrict__ a1,
    const float* __restrict__ Wo, const int* __restrict__ mask,
    float* __restrict__ out)
{
    __shared__ unsigned short s_wfHi[5120];       // 10 KB  weff A-frags hi
    __shared__ unsigned short s_wfLo[5120];       // 10 KB
    __shared__ float s_logits[208];
    __shared__ float s_biasq[H0];
    __shared__ float s_a0[H0];
    __shared__ float s_b1p[48], s_a1p[48], s_Wop[48];
    __shared__ float s_w[BLOCK];
    __shared__ float s_red[8];
    __shared__ float s_part[4][D];

    const int tid  = threadIdx.x;
    const int b    = blockIdx.x;
    const int wv   = tid >> 6;
    const int lane = tid & 63;
    const int l16  = lane & 15;
    const int quad = lane >> 4;
    const bool hiQ = (quad >= 2);
    const float* qb = q + (size_t)b * D;
    const float* kb_base = k + (size_t)b * T * D;

    // ---- early global issues: mask + first k tile (latency hides under fold)
    const int mval = (tid < T) ? mask[(size_t)b * T + tid] : 0;
    float4 kc0, kc1, kc2, kc3;
    {
        int row = wv * 16 + l16; if (row > T - 1) row = T - 1;
        const float* kr = kb_base + (size_t)row * D + quad * 8;
        kc0 = *(const float4*)(kr);
        kc1 = *(const float4*)(kr + 4);
        kc2 = *(const float4*)(kr + 32);
        kc3 = *(const float4*)(kr + 36);
    }

    // ---- Phase 0: fold weff into LDS A-frags (coalesced W0 reads) ----
    const float* Wk = W0 + 64 * H0;
    const float* Wd = W0 + 128 * H0;
    const float* Wp = W0 + 192 * H0;
    #pragma unroll 4
    for (int it = 0; it < 20; ++it) {
        const int e  = it * 256 + tid;            // e in [0, 5120)
        const int kk = e / 80, h = e - kk * 80;
        const float w = Wk[e] - Wd[e] + qb[kk] * Wp[e];
        const unsigned short hb = bf16h(w);
        const unsigned short lb = bf16h(w - __uint_as_float((unsigned)hb << 16));
        // A-frag: lane = ((kk>>3)&3)*16 + (h&15), j = kk&7
        const int off = (((kk >> 5) * 5 + (h >> 4)) << 9)
                      + (((((kk >> 3) & 3) << 4) + (h & 15)) << 3) + (kk & 7);
        s_wfHi[off] = hb; s_wfLo[off] = lb;
    }
    // biasq + per-feature consts
    if (tid < H0) {
        float acc = b0[tid];
        #pragma unroll 8
        for (int d = 0; d < D; ++d)
            acc = fmaf(qb[d], W0[d * H0 + tid] + W0[(128 + d) * H0 + tid], acc);
        s_biasq[tid] = acc;
        s_a0[tid]    = a0[tid];
    }
    if (tid < 48) {
        s_b1p[tid] = (tid < H1) ? b1[tid] : 0.0f;
        s_a1p[tid] = (tid < H1) ? a1[tid] : 0.0f;
        s_Wop[tid] = (tid < H1) ? Wo[tid] : 0.0f;
    }
    __syncthreads();

    // bpermute source byte-addrs: lane (2*(quad&1) + {0,1})*16 + l16
    const int addr0 = (((quad & 1) << 5) + l16) << 2;
    const int addr1 = addr0 + 64;

// Layer-1 h-tile HT: 6 MFMAs -> PReLU -> pack into named uint2 HW/LW
#define L1_HT(HT, HW, LW) { \
    f32x4 acc_ = {0.0f, 0.0f, 0.0f, 0.0f}; \
    { short8 Ah_ = *(const short8*)&s_wfHi[(0 * 5 + HT) * 512 + lane * 8]; \
      short8 Al_ = *(const short8*)&s_wfLo[(0 * 5 + HT) * 512 + lane * 8]; \
      acc_ = MFMA(Ah_, kbhi0, acc_); \
      acc_ = MFMA(Ah_, kblo0, acc_); \
      acc_ = MFMA(Al_, kbhi0, acc_); } \
    { short8 Ah_ = *(const short8*)&s_wfHi[(1 * 5 + HT) * 512 + lane * 8]; \
      short8 Al_ = *(const short8*)&s_wfLo[(1 * 5 + HT) * 512 + lane * 8]; \
      acc_ = MFMA(Ah_, kbhi1, acc_); \
      acc_ = MFMA(Ah_, kblo1, acc_); \
      acc_ = MFMA(Al_, kbhi1, acc_); } \
    const int hb_ = HT * 16 + quad * 4; \
    const float x0_ = acc_[0] + s_biasq[hb_ + 0]; \
    const float x1_ = acc_[1] + s_biasq[hb_ + 1]; \
    const float x2_ = acc_[2] + s_biasq[hb_ + 2]; \
    const float x3_ = acc_[3] + s_biasq[hb_ + 3]; \
    const float f0_ = (x0_ >= 0.0f) ? x0_ : s_a0[hb_ + 0] * x0_; \
    const float f1_ = (x1_ >= 0.0f) ? x1_ : s_a0[hb_ + 1] * x1_; \
    const float f2_ = (x2_ >= 0.0f) ? x2_ : s_a0[hb_ + 2] * x2_; \
    const float f3_ = (x3_ >= 0.0f) ? x3_ : s_a0[hb_ + 3] * x3_; \
    pk_split(f0_, f1_, HW.x, LW.x); \
    pk_split(f2_, f3_, HW.y, LW.y); }

// Transpose k2-step from (HA=even-ht, HB=odd-ht) words to A-frag AHI/ALO.
// For the last k2-step pass HA==HB: the bogus upper-quad values multiply
// the zero pad rows of the W1 frags -> contribute exactly 0.
#define TRN(HA, HB, LA, LB, AHI, ALO) { \
    int h0_ = BPERM(addr0, HA.x), h1_ = BPERM(addr0, HA.y); \
    int h2_ = BPERM(addr1, HA.x), h3_ = BPERM(addr1, HA.y); \
    int g0_ = BPERM(addr0, HB.x), g1_ = BPERM(addr0, HB.y); \
    int g2_ = BPERM(addr1, HB.x), g3_ = BPERM(addr1, HB.y); \
    AHI = mk8(hiQ ? g0_ : h0_, hiQ ? g1_ : h1_, hiQ ? g2_ : h2_, hiQ ? g3_ : h3_); \
    int l0_ = BPERM(addr0, LA.x), l1_ = BPERM(addr0, LA.y); \
    int l2_ = BPERM(addr1, LA.x), l3_ = BPERM(addr1, LA.y); \
    int m0_ = BPERM(addr0, LB.x), m1_ = BPERM(addr0, LB.y); \
    int m2_ = BPERM(addr1, LB.x), m3_ = BPERM(addr1, LB.y); \
    ALO = mk8(hiQ ? m0_ : l0_, hiQ ? m1_ : l1_, hiQ ? m2_ : l2_, hiQ ? m3_ : l3_); }

// Layer-2 k2-slice K2S: 9 MFMAs (B-frags from global ws, L2-resident) into
// the 3 persistent accumulators accn0..2
#define L2_K2S(K2S, AHI, ALO) { \
    { short8 bh_ = *(const short8*)&w1fHi[(K2S * 3 + 0) * 512 + lane * 8]; \
      short8 bl_ = *(const short8*)&w1fLo[(K2S * 3 + 0) * 512 + lane * 8]; \
      accn0 = MFMA(AHI, bh_, accn0); \
      accn0 = MFMA(AHI, bl_, accn0); \
      accn0 = MFMA(ALO, bh_, accn0); } \
    { short8 bh_ = *(const short8*)&w1fHi[(K2S * 3 + 1) * 512 + lane * 8]; \
      short8 bl_ = *(const short8*)&w1fLo[(K2S * 3 + 1) * 512 + lane * 8]; \
      accn1 = MFMA(AHI, bh_, accn1); \
      accn1 = MFMA(AHI, bl_, accn1); \
      accn1 = MFMA(ALO, bh_, accn1); } \
    { short8 bh_ = *(const short8*)&w1fHi[(K2S * 3 + 2) * 512 + lane * 8]; \
      short8 bl_ = *(const short8*)&w1fLo[(K2S * 3 + 2) * 512 + lane * 8]; \
      accn2 = MFMA(AHI, bh_, accn2); \
      accn2 = MFMA(AHI, bl_, accn2); \
      accn2 = MFMA(ALO, bh_, accn2); } }

// Layer-2 epilogue for n-tile NT2: PReLU + head dot into part0..3
#define L2_EPI(NT2, ACC) { \
    const int g_ = NT2 * 16 + l16; \
    const float bg_ = s_b1p[g_], ag_ = s_a1p[g_], wg_ = s_Wop[g_]; \
    { const float x_ = ACC[0] + bg_; part0 = fmaf((x_ >= 0.0f) ? x_ : ag_ * x_, wg_, part0); } \
    { const float x_ = ACC[1] + bg_; part1 = fmaf((x_ >= 0.0f) ? x_ : ag_ * x_, wg_, part1); } \
    { const float x_ = ACC[2] + bg_; part2 = fmaf((x_ >= 0.0f) ? x_ : ag_ * x_, wg_, part2); } \
    { const float x_ = ACC[3] + bg_; part3 = fmaf((x_ >= 0.0f) ? x_ : ag_ * x_, wg_, part3); } }

    // ---- Phase 1: per-wave M-tiles; kc reloaded in place (free prefetch) ----
    for (int mt = wv; mt < 13; mt += 4) {
        // K^T B-fragments (lane: n=l16 row of K, k=quad*8+j), split bf16
        short8 kbhi0, kblo0, kbhi1, kblo1;
        {
            unsigned h0_, l0_, h1_, l1_, h2_, l2_, h3_, l3_;
            pk_split(kc0.x, kc0.y, h0_, l0_);
            pk_split(kc0.z, kc0.w, h1_, l1_);
            pk_split(kc1.x, kc1.y, h2_, l2_);
            pk_split(kc1.z, kc1.w, h3_, l3_);
            kbhi0 = mk8((int)h0_, (int)h1_, (int)h2_, (int)h3_);
            kblo0 = mk8((int)l0_, (int)l1_, (int)l2_, (int)l3_);
            pk_split(kc2.x, kc2.y, h0_, l0_);
            pk_split(kc2.z, kc2.w, h1_, l1_);
            pk_split(kc3.x, kc3.y, h2_, l2_);
            pk_split(kc3.z, kc3.w, h3_, l3_);
            kbhi1 = mk8((int)h0_, (int)h1_, (int)h2_, (int)h3_);
            kblo1 = mk8((int)l0_, (int)l1_, (int)l2_, (int)l3_);
        }
        // kc is dead now -> reload in place for tile mt+4 (zero extra regs)
        if (mt + 4 < 13) {
            int row = (mt + 4) * 16 + l16; if (row > T - 1) row = T - 1;
            const float* kr = kb_base + (size_t)row * D + quad * 8;
            kc0 = *(const float4*)(kr);
            kc1 = *(const float4*)(kr + 4);
            kc2 = *(const float4*)(kr + 32);
            kc3 = *(const float4*)(kr + 36);
        }
        // ---- Layer 1: 5 h-tiles -> named split-bf16 words ----
        uint2 hw0, hw1, hw2, hw3, hw4, lw0, lw1, lw2, lw3, lw4;
        L1_HT(0, hw0, lw0)
        L1_HT(1, hw1, lw1)
        L1_HT(2, hw2, lw2)
        L1_HT(3, hw3, lw3)
        L1_HT(4, hw4, lw4)
        // ---- Layer 2: interleaved TRN + MFMA per k2-slice ----
        f32x4 accn0 = {0.0f, 0.0f, 0.0f, 0.0f};
        f32x4 accn1 = {0.0f, 0.0f, 0.0f, 0.0f};
        f32x4 accn2 = {0.0f, 0.0f, 0.0f, 0.0f};
        {
            short8 a2hi, a2lo;
            TRN(hw0, hw1, lw0, lw1, a2hi, a2lo)
            L2_K2S(0, a2hi, a2lo)
        }
        {
            short8 a2hi, a2lo;
            TRN(hw2, hw3, lw2, lw3, a2hi, a2lo)
            L2_K2S(1, a2hi, a2lo)
        }
        {
            short8 a2hi, a2lo;
            TRN(hw4, hw4, lw4, lw4, a2hi, a2lo)  // upper half bogus x zero B rows
            L2_K2S(2, a2hi, a2lo)
        }
        // ---- epilogue + head ----
        float part0 = 0.0f, part1 = 0.0f, part2 = 0.0f, part3 = 0.0f;
        L2_EPI(0, accn0)
        L2_EPI(1, accn1)
        L2_EPI(2, accn2)
        // reduce over the 16 g-cols (lane bits 0..3)
        #pragma unroll
        for (int off = 1; off < 16; off <<= 1) {
            part0 += __shfl_xor(part0, off);
            part1 += __shfl_xor(part1, off);
            part2 += __shfl_xor(part2, off);
            part3 += __shfl_xor(part3, off);
        }
        if (l16 == 0) {
            float4 p = {part0, part1, part2, part3};
            *(float4*)&s_logits[mt * 16 + quad * 4] = p;
        }
    }
    __syncthreads();

    // ---- Phase 2: mask + softmax over T (pads -> -inf => exp 0) ----
    float logit = -INFINITY;
    if (tid < T)
        logit = (mval == 0) ? NEG_INF_V : s_logits[tid];

    float m = logit;
    #pragma unroll
    for (int off = 32; off > 0; off >>= 1) m = fmaxf(m, __shfl_xor(m, off));
    if (lane == 0) s_red[wv] = m;
    __syncthreads();
    m = fmaxf(fmaxf(s_red[0], s_red[1]), fmaxf(s_red[2], s_red[3]));
    const float e = expf(logit - m);
    s_w[tid] = e;
    float ssum = e;
    #pragma unroll
    for (int off = 32; off > 0; off >>= 1) ssum += __shfl_xor(ssum, off);
    if (lane == 0) s_red[4 + wv] = ssum;
    __syncthreads();
    const float inv = 1.0f / (s_red[4] + s_red[5] + s_red[6] + s_red[7]);

    // ---- out[b,d] = sum_t w_t * v[b,t,d] (coalesced in d) ----
    const int d = tid & (D - 1);
    const int c = tid >> 6;
    constexpr int TC = T / 4;          // 50
    float acc2 = 0.0f;
    const float* vp = v + ((size_t)b * T + c * TC) * D + d;
    #pragma unroll 10
    for (int t = 0; t < TC; ++t)
        acc2 = fmaf(s_w[c * TC + t], vp[t * D], acc2);
    s_part[c][d] = acc2;
    __syncthreads();
    if (tid < D) {
        out[(size_t)b * D + tid] =
            (s_part[0][tid] + s_part[1][tid] + s_part[2][tid] + s_part[3][tid]) * inv;
    }
}

extern "C" void kernel_launch(void* const* d_in, const int* in_sizes, int n_in,
                              void* d_out, int out_size, void* d_ws, size_t ws_size,
                              hipStream_t stream) {
    const float* q  = (const float*)d_in[0];
    const float* k  = (const float*)d_in[1];
    const float* v  = (const float*)d_in[2];
    const float* W0 = (const float*)d_in[3];
    const float* b0 = (const float*)d_in[4];
    const float* a0 = (const float*)d_in[5];
    const float* W1 = (const float*)d_in[6];
    const float* b1 = (const float*)d_in[7];
    const float* a1 = (const float*)d_in[8];
    const float* Wo = (const float*)d_in[9];
    const int*  mask = (const int*)d_in[11];
    float* out = (float*)d_out;

    const int B = in_sizes[0] / D;            // 2048

    short* w1fHi = (short*)d_ws;              // 4608 shorts
    short* w1fLo = w1fHi + 4608;              // 4608 shorts (18432 B total)

    fold_w1<<<dim3(1), dim3(256), 0, stream>>>(W1, w1fHi, w1fLo);
    attn_fused<<<dim3(B), dim3(BLOCK), 0, stream>>>(
        q, k, v, W0, b0, a0, w1fHi, w1fLo, b1, a1, Wo, mask, out);
}

// Round 9
// 298.020 us; speedup vs baseline: 1.4876x; 1.4876x over previous
//
#include <hip/hip_runtime.h>
#include <hip/hip_bf16.h>
#include <math.h>

constexpr int D  = 64;
constexpr int T  = 200;
constexpr int H0 = 80;
constexpr int H1 = 40;
constexpr int BLOCK = 256;
constexpr float NEG_INF_V = -4294967295.0f;

typedef short short8 __attribute__((ext_vector_type(8)));
typedef float f32x4 __attribute__((ext_vector_type(4)));
typedef int   int4v __attribute__((ext_vector_type(4)));

// RNE fp32->bf16 (hardware cvt), raw bits
__device__ inline unsigned short bf16h(float x) {
    __hip_bfloat16 t = __float2bfloat16(x);
    union { __hip_bfloat16 v; unsigned short u; } c; c.v = t; return c.u;
}
// RNE packed pair: low16 = bf16(a), high16 = bf16(b)
__device__ inline unsigned pk_bf16(float a, float b) {
    float2 f2; f2.x = a; f2.y = b;
    __hip_bfloat162 t = __float22bfloat162_rn(f2);
    union { __hip_bfloat162 v; unsigned u; } c; c.v = t; return c.u;
}
// split pair to (hi word, lo word)
__device__ inline void pk_split(float a, float b, unsigned& hi, unsigned& lo) {
    hi = pk_bf16(a, b);
    const float e0 = a - __uint_as_float(hi << 16);
    const float e1 = b - __uint_as_float(hi & 0xffff0000u);
    lo = pk_bf16(e0, e1);
}
__device__ inline short8 mk8(int w0, int w1, int w2, int w3) {
    union { int4v i; short8 s; } u;
    u.i = (int4v){w0, w1, w2, w3};
    return u.s;
}
#define BPERM(ad, v) __builtin_amdgcn_ds_bpermute((ad), (int)(v))
#define MFMA(A, B, C) __builtin_amdgcn_mfma_f32_16x16x32_bf16((A), (B), (C), 0, 0, 0)

// ============ Pre-kernel: fold W1 into split-bf16 B-frags in ws ============
// Batch-independent; folded ONCE (R4's per-block redundant fold cost ~44us).
// B-frag layout (16x16x32): frag (k2s,nt2), lane holds B[k2=k2s*32+quad*8+j]
// [n=nt2*16+l16]; zero-padded 96x48 (pad rows/cols EXACTLY 0.0 -> main kernel
// may feed garbage-but-finite A there).
__global__ __launch_bounds__(256) void fold_w1(
    const float* __restrict__ W1, short* __restrict__ w1fHi,
    short* __restrict__ w1fLo)
{
    const int tid = threadIdx.x;
    for (int e = tid; e < 4608; e += 256) {
        const int k2 = e / 48, n = e - k2 * 48;
        const float w = (k2 < H0 && n < H1) ? W1[k2 * H1 + n] : 0.0f;
        const unsigned short hb = bf16h(w);
        const unsigned short lb = bf16h(w - __uint_as_float((unsigned)hb << 16));
        const int off = (((k2 >> 5) * 3 + (n >> 4)) << 9)
                      + (((((k2 >> 3) & 3) << 4) + (n & 15)) << 3) + (k2 & 7);
        w1fHi[off] = hb; w1fLo[off] = lb;
    }
}

// ============ Fully fused main kernel ============
// One block per batch b, 4 waves, LDS ~44 KB, VGPR cap 128 ((256,2)) -> the
// only spill-free operating point (R7 proved: forcing occupancy -> spill-BW-
// bound). At fixed 2 blocks/CU, PER-WAVE LATENCY is throughput: w1f B-frags
// are staged global->LDS once per block (copy loads issued BEFORE the weff
// fold so L2 latency hides under fold VALU); per-mt B-frag reads become
// conflict-free ds_read_b128 (~120cyc) instead of L2 round-trips (~300+cyc,
// 3 exposed waits per mt in R6).
// Phase 0: stage w1f; fold weff[kk][h] = W0[64+kk][h]-W0[128+kk][h]
//   +q_kk*W0[192+kk][h] into split-bf16 MFMA A-frags in LDS (m=h, k=kk);
//   biasq[h] = b0[h] + sum_d q_d*(W0[d][h]+W0[128+d][h]). Mask + first
//   k-tile issued first of all.
// Phase 1: wave w owns M-tiles {w, w+4, ...} of 13 (M=200 pad 208).
//   Layer1: C1^T = weff(A) x K^T(B): lane holds h0[h=ht*16+quad*4+reg][m=l16];
//   PReLU in-register; pack to split-bf16 named uint2 scalars (no arrays ->
//   no rule-#20 scratch). kc0..3 reloaded IN PLACE for tile mt+4 right after
//   KBUILD consumes them (prefetch with zero extra live regs). Layer2
//   INTERLEAVED per k2-slice: TRN (quad-level ds_bpermute transpose) makes
//   ONE a2hi/a2lo pair, immediately consumed by 9 MFMAs into 3 persistent
//   f32x4 accumulators; source hw/lw pair dies (narrow live window, R7).
//   k2s=2 feeds TRN(hw4,hw4): garbage upper half multiplies ZERO pad rows of
//   W1 frags. Head dot + shfl_xor -> s_logits.
// Phase 2: softmax over T + out[b,d] = sum_t w_t v[b,t,d].
__global__ __launch_bounds__(BLOCK, 2) void attn_fused(
    const float* __restrict__ q, const float* __restrict__ k,
    const float* __restrict__ v, const float* __restrict__ W0,
    const float* __restrict__ b0, const float* __restrict__ a0,
    const short* __restrict__ w1fHi, const short* __restrict__ w1fLo,
    const float* __restrict__ b1, const float* __restrict__ a1,
    const float* __restrict__ Wo, const int* __restrict__ mask,
    float* __restrict__ out)
{
    __shared__ unsigned short s_wfHi[5120];       // 10 KB  weff A-frags hi
    __shared__ unsigned short s_wfLo[5120];       // 10 KB
    __shared__ unsigned short s_w1Hi[4608];       // 9 KB   W1 B-frags hi
    __shared__ unsigned short s_w1Lo[4608];       // 9 KB
    __shared__ float s_logits[208];
    __shared__ float s_biasq[H0];
    __shared__ float s_a0[H0];
    __shared__ float s_b1p[48], s_a1p[48], s_Wop[48];
    __shared__ float s_w[BLOCK];
    __shared__ float s_red[8];
    __shared__ float s_part[4][D];

    const int tid  = threadIdx.x;
    const int b    = blockIdx.x;
    const int wv   = tid >> 6;
    const int lane = tid & 63;
    const int l16  = lane & 15;
    const int quad = lane >> 4;
    const bool hiQ = (quad >= 2);
    const float* qb = q + (size_t)b * D;
    const float* kb_base = k + (size_t)b * T * D;

    // ---- early global issues: mask + first k tile (latency hides under fold)
    const int mval = (tid < T) ? mask[(size_t)b * T + tid] : 0;
    float4 kc0, kc1, kc2, kc3;
    {
        int row = wv * 16 + l16; if (row > T - 1) row = T - 1;
        const float* kr = kb_base + (size_t)row * D + quad * 8;
        kc0 = *(const float4*)(kr);
        kc1 = *(const float4*)(kr + 4);
        kc2 = *(const float4*)(kr + 32);
        kc3 = *(const float4*)(kr + 36);
    }
    // ---- stage pre-folded w1f into LDS (16B chunks; loads issue here,
    //      latency hides under the weff fold below) ----
    {
        const short8* srcH = (const short8*)w1fHi;
        const short8* srcL = (const short8*)w1fLo;
        short8* dstH = (short8*)s_w1Hi;
        short8* dstL = (short8*)s_w1Lo;
        #pragma unroll
        for (int i = 0; i < 2; ++i) {
            dstH[tid + i * 256] = srcH[tid + i * 256];
            dstL[tid + i * 256] = srcL[tid + i * 256];
        }
        if (tid < 64) {
            dstH[tid + 512] = srcH[tid + 512];
            dstL[tid + 512] = srcL[tid + 512];
        }
    }

    // ---- Phase 0: fold weff into LDS A-frags (coalesced W0 reads) ----
    const float* Wk = W0 + 64 * H0;
    const float* Wd = W0 + 128 * H0;
    const float* Wp = W0 + 192 * H0;
    #pragma unroll 4
    for (int it = 0; it < 20; ++it) {
        const int e  = it * 256 + tid;            // e in [0, 5120)
        const int kk = e / 80, h = e - kk * 80;
        const float w = Wk[e] - Wd[e] + qb[kk] * Wp[e];
        const unsigned short hb = bf16h(w);
        const unsigned short lb = bf16h(w - __uint_as_float((unsigned)hb << 16));
        // A-frag: lane = ((kk>>3)&3)*16 + (h&15), j = kk&7
        const int off = (((kk >> 5) * 5 + (h >> 4)) << 9)
                      + (((((kk >> 3) & 3) << 4) + (h & 15)) << 3) + (kk & 7);
        s_wfHi[off] = hb; s_wfLo[off] = lb;
    }
    // biasq + per-feature consts
    if (tid < H0) {
        float acc = b0[tid];
        #pragma unroll 8
        for (int d = 0; d < D; ++d)
            acc = fmaf(qb[d], W0[d * H0 + tid] + W0[(128 + d) * H0 + tid], acc);
        s_biasq[tid] = acc;
        s_a0[tid]    = a0[tid];
    }
    if (tid < 48) {
        s_b1p[tid] = (tid < H1) ? b1[tid] : 0.0f;
        s_a1p[tid] = (tid < H1) ? a1[tid] : 0.0f;
        s_Wop[tid] = (tid < H1) ? Wo[tid] : 0.0f;
    }
    __syncthreads();

    // bpermute source byte-addrs: lane (2*(quad&1) + {0,1})*16 + l16
    const int addr0 = (((quad & 1) << 5) + l16) << 2;
    const int addr1 = addr0 + 64;

// Layer-1 h-tile HT: 6 MFMAs -> PReLU -> pack into named uint2 HW/LW
#define L1_HT(HT, HW, LW) { \
    f32x4 acc_ = {0.0f, 0.0f, 0.0f, 0.0f}; \
    { short8 Ah_ = *(const short8*)&s_wfHi[(0 * 5 + HT) * 512 + lane * 8]; \
      short8 Al_ = *(const short8*)&s_wfLo[(0 * 5 + HT) * 512 + lane * 8]; \
      acc_ = MFMA(Ah_, kbhi0, acc_); \
      acc_ = MFMA(Ah_, kblo0, acc_); \
      acc_ = MFMA(Al_, kbhi0, acc_); } \
    { short8 Ah_ = *(const short8*)&s_wfHi[(1 * 5 + HT) * 512 + lane * 8]; \
      short8 Al_ = *(const short8*)&s_wfLo[(1 * 5 + HT) * 512 + lane * 8]; \
      acc_ = MFMA(Ah_, kbhi1, acc_); \
      acc_ = MFMA(Ah_, kblo1, acc_); \
      acc_ = MFMA(Al_, kbhi1, acc_); } \
    const int hb_ = HT * 16 + quad * 4; \
    const float x0_ = acc_[0] + s_biasq[hb_ + 0]; \
    const float x1_ = acc_[1] + s_biasq[hb_ + 1]; \
    const float x2_ = acc_[2] + s_biasq[hb_ + 2]; \
    const float x3_ = acc_[3] + s_biasq[hb_ + 3]; \
    const float f0_ = (x0_ >= 0.0f) ? x0_ : s_a0[hb_ + 0] * x0_; \
    const float f1_ = (x1_ >= 0.0f) ? x1_ : s_a0[hb_ + 1] * x1_; \
    const float f2_ = (x2_ >= 0.0f) ? x2_ : s_a0[hb_ + 2] * x2_; \
    const float f3_ = (x3_ >= 0.0f) ? x3_ : s_a0[hb_ + 3] * x3_; \
    pk_split(f0_, f1_, HW.x, LW.x); \
    pk_split(f2_, f3_, HW.y, LW.y); }

// Transpose k2-step from (HA=even-ht, HB=odd-ht) words to A-frag AHI/ALO.
// For the last k2-step pass HA==HB: the bogus upper-quad values multiply
// the zero pad rows of the W1 frags -> contribute exactly 0.
#define TRN(HA, HB, LA, LB, AHI, ALO) { \
    int h0_ = BPERM(addr0, HA.x), h1_ = BPERM(addr0, HA.y); \
    int h2_ = BPERM(addr1, HA.x), h3_ = BPERM(addr1, HA.y); \
    int g0_ = BPERM(addr0, HB.x), g1_ = BPERM(addr0, HB.y); \
    int g2_ = BPERM(addr1, HB.x), g3_ = BPERM(addr1, HB.y); \
    AHI = mk8(hiQ ? g0_ : h0_, hiQ ? g1_ : h1_, hiQ ? g2_ : h2_, hiQ ? g3_ : h3_); \
    int l0_ = BPERM(addr0, LA.x), l1_ = BPERM(addr0, LA.y); \
    int l2_ = BPERM(addr1, LA.x), l3_ = BPERM(addr1, LA.y); \
    int m0_ = BPERM(addr0, LB.x), m1_ = BPERM(addr0, LB.y); \
    int m2_ = BPERM(addr1, LB.x), m3_ = BPERM(addr1, LB.y); \
    ALO = mk8(hiQ ? m0_ : l0_, hiQ ? m1_ : l1_, hiQ ? m2_ : l2_, hiQ ? m3_ : l3_); }

// Layer-2 k2-slice K2S: 9 MFMAs (B-frags from LDS, conflict-free b128) into
// the 3 persistent accumulators accn0..2
#define L2_K2S(K2S, AHI, ALO) { \
    { short8 bh_ = *(const short8*)&s_w1Hi[(K2S * 3 + 0) * 512 + lane * 8]; \
      short8 bl_ = *(const short8*)&s_w1Lo[(K2S * 3 + 0) * 512 + lane * 8]; \
      accn0 = MFMA(AHI, bh_, accn0); \
      accn0 = MFMA(AHI, bl_, accn0); \
      accn0 = MFMA(ALO, bh_, accn0); } \
    { short8 bh_ = *(const short8*)&s_w1Hi[(K2S * 3 + 1) * 512 + lane * 8]; \
      short8 bl_ = *(const short8*)&s_w1Lo[(K2S * 3 + 1) * 512 + lane * 8]; \
      accn1 = MFMA(AHI, bh_, accn1); \
      accn1 = MFMA(AHI, bl_, accn1); \
      accn1 = MFMA(ALO, bh_, accn1); } \
    { short8 bh_ = *(const short8*)&s_w1Hi[(K2S * 3 + 2) * 512 + lane * 8]; \
      short8 bl_ = *(const short8*)&s_w1Lo[(K2S * 3 + 2) * 512 + lane * 8]; \
      accn2 = MFMA(AHI, bh_, accn2); \
      accn2 = MFMA(AHI, bl_, accn2); \
      accn2 = MFMA(ALO, bh_, accn2); } }

// Layer-2 epilogue for n-tile NT2: PReLU + head dot into part0..3
#define L2_EPI(NT2, ACC) { \
    const int g_ = NT2 * 16 + l16; \
    const float bg_ = s_b1p[g_], ag_ = s_a1p[g_], wg_ = s_Wop[g_]; \
    { const float x_ = ACC[0] + bg_; part0 = fmaf((x_ >= 0.0f) ? x_ : ag_ * x_, wg_, part0); } \
    { const float x_ = ACC[1] + bg_; part1 = fmaf((x_ >= 0.0f) ? x_ : ag_ * x_, wg_, part1); } \
    { const float x_ = ACC[2] + bg_; part2 = fmaf((x_ >= 0.0f) ? x_ : ag_ * x_, wg_, part2); } \
    { const float x_ = ACC[3] + bg_; part3 = fmaf((x_ >= 0.0f) ? x_ : ag_ * x_, wg_, part3); } }

    // ---- Phase 1: per-wave M-tiles; kc reloaded in place (free prefetch) ----
    for (int mt = wv; mt < 13; mt += 4) {
        // K^T B-fragments (lane: n=l16 row of K, k=quad*8+j), split bf16
        short8 kbhi0, kblo0, kbhi1, kblo1;
        {
            unsigned h0_, l0_, h1_, l1_, h2_, l2_, h3_, l3_;
            pk_split(kc0.x, kc0.y, h0_, l0_);
            pk_split(kc0.z, kc0.w, h1_, l1_);
            pk_split(kc1.x, kc1.y, h2_, l2_);
            pk_split(kc1.z, kc1.w, h3_, l3_);
            kbhi0 = mk8((int)h0_, (int)h1_, (int)h2_, (int)h3_);
            kblo0 = mk8((int)l0_, (int)l1_, (int)l2_, (int)l3_);
            pk_split(kc2.x, kc2.y, h0_, l0_);
            pk_split(kc2.z, kc2.w, h1_, l1_);
            pk_split(kc3.x, kc3.y, h2_, l2_);
            pk_split(kc3.z, kc3.w, h3_, l3_);
            kbhi1 = mk8((int)h0_, (int)h1_, (int)h2_, (int)h3_);
            kblo1 = mk8((int)l0_, (int)l1_, (int)l2_, (int)l3_);
        }
        // kc is dead now -> reload in place for tile mt+4 (zero extra regs)
        if (mt + 4 < 13) {
            int row = (mt + 4) * 16 + l16; if (row > T - 1) row = T - 1;
            const float* kr = kb_base + (size_t)row * D + quad * 8;
            kc0 = *(const float4*)(kr);
            kc1 = *(const float4*)(kr + 4);
            kc2 = *(const float4*)(kr + 32);
            kc3 = *(const float4*)(kr + 36);
        }
        // ---- Layer 1: 5 h-tiles -> named split-bf16 words ----
        uint2 hw0, hw1, hw2, hw3, hw4, lw0, lw1, lw2, lw3, lw4;
        L1_HT(0, hw0, lw0)
        L1_HT(1, hw1, lw1)
        L1_HT(2, hw2, lw2)
        L1_HT(3, hw3, lw3)
        L1_HT(4, hw4, lw4)
        // ---- Layer 2: interleaved TRN + MFMA per k2-slice ----
        f32x4 accn0 = {0.0f, 0.0f, 0.0f, 0.0f};
        f32x4 accn1 = {0.0f, 0.0f, 0.0f, 0.0f};
        f32x4 accn2 = {0.0f, 0.0f, 0.0f, 0.0f};
        {
            short8 a2hi, a2lo;
            TRN(hw0, hw1, lw0, lw1, a2hi, a2lo)
            L2_K2S(0, a2hi, a2lo)
        }
        {
            short8 a2hi, a2lo;
            TRN(hw2, hw3, lw2, lw3, a2hi, a2lo)
            L2_K2S(1, a2hi, a2lo)
        }
        {
            short8 a2hi, a2lo;
            TRN(hw4, hw4, lw4, lw4, a2hi, a2lo)  // upper half bogus x zero B rows
            L2_K2S(2, a2hi, a2lo)
        }
        // ---- epilogue + head ----
        float part0 = 0.0f, part1 = 0.0f, part2 = 0.0f, part3 = 0.0f;
        L2_EPI(0, accn0)
        L2_EPI(1, accn1)
        L2_EPI(2, accn2)
        // reduce over the 16 g-cols (lane bits 0..3)
        #pragma unroll
        for (int off = 1; off < 16; off <<= 1) {
            part0 += __shfl_xor(part0, off);
            part1 += __shfl_xor(part1, off);
            part2 += __shfl_xor(part2, off);
            part3 += __shfl_xor(part3, off);
        }
        if (l16 == 0) {
            float4 p = {part0, part1, part2, part3};
            *(float4*)&s_logits[mt * 16 + quad * 4] = p;
        }
    }
    __syncthreads();

    // ---- Phase 2: mask + softmax over T (pads -> -inf => exp 0) ----
    float logit = -INFINITY;
    if (tid < T)
        logit = (mval == 0) ? NEG_INF_V : s_logits[tid];

    float m = logit;
    #pragma unroll
    for (int off = 32; off > 0; off >>= 1) m = fmaxf(m, __shfl_xor(m, off));
    if (lane == 0) s_red[wv] = m;
    __syncthreads();
    m = fmaxf(fmaxf(s_red[0], s_red[1]), fmaxf(s_red[2], s_red[3]));
    const float e = expf(logit - m);
    s_w[tid] = e;
    float ssum = e;
    #pragma unroll
    for (int off = 32; off > 0; off >>= 1) ssum += __shfl_xor(ssum, off);
    if (lane == 0) s_red[4 + wv] = ssum;
    __syncthreads();
    const float inv = 1.0f / (s_red[4] + s_red[5] + s_red[6] + s_red[7]);

    // ---- out[b,d] = sum_t w_t * v[b,t,d] (coalesced in d) ----
    const int d = tid & (D - 1);
    const int c = tid >> 6;
    constexpr int TC = T / 4;          // 50
    float acc2 = 0.0f;
    const float* vp = v + ((size_t)b * T + c * TC) * D + d;
    #pragma unroll 10
    for (int t = 0; t < TC; ++t)
        acc2 = fmaf(s_w[c * TC + t], vp[t * D], acc2);
    s_part[c][d] = acc2;
    __syncthreads();
    if (tid < D) {
        out[(size_t)b * D + tid] =
            (s_part[0][tid] + s_part[1][tid] + s_part[2][tid] + s_part[3][tid]) * inv;
    }
}

extern "C" void kernel_launch(void* const* d_in, const int* in_sizes, int n_in,
                              void* d_out, int out_size, void* d_ws, size_t ws_size,
                              hipStream_t stream) {
    const float* q  = (const float*)d_in[0];
    const float* k  = (const float*)d_in[1];
    const float* v  = (const float*)d_in[2];
    const float* W0 = (const float*)d_in[3];
    const float* b0 = (const float*)d_in[4];
    const float* a0 = (const float*)d_in[5];
    const float* W1 = (const float*)d_in[6];
    const float* b1 = (const float*)d_in[7];
    const float* a1 = (const float*)d_in[8];
    const float* Wo = (const float*)d_in[9];
    const int*  mask = (const int*)d_in[11];
    float* out = (float*)d_out;

    const int B = in_sizes[0] / D;            // 2048

    short* w1fHi = (short*)d_ws;              // 4608 shorts
    short* w1fLo = w1fHi + 4608;              // 4608 shorts (18432 B total)

    fold_w1<<<dim3(1), dim3(256), 0, stream>>>(W1, w1fHi, w1fLo);
    attn_fused<<<dim3(B), dim3(BLOCK), 0, stream>>>(
        q, k, v, W0, b0, a0, w1fHi, w1fLo, b1, a1, Wo, mask, out);
}